// Round 1
// baseline (2365.906 us; speedup 1.0000x reference)
//
#include <hip/hip_runtime.h>

#define THREADS 256

__global__ void k_deg(const int* __restrict__ dst, float* __restrict__ deg, int E) {
    int t = blockIdx.x * blockDim.x + threadIdx.x;
    if (t < E) atomicAdd(&deg[dst[t]], 1.0f);
}

__global__ void k_dinv(float* __restrict__ d, int N) {
    int t = blockIdx.x * blockDim.x + threadIdx.x;
    if (t < N) d[t] = rsqrtf(d[t] + 1.0f);
}

__global__ void k_norm(const int* __restrict__ src, const int* __restrict__ dst,
                       const float* __restrict__ dinv, float* __restrict__ norm, int E) {
    int t = blockIdx.x * blockDim.x + threadIdx.x;
    if (t < E) norm[t] = dinv[src[t]] * dinv[dst[t]];
}

// Layer-1 "GEMM": x is [N,1], W1 is [1,128] -> outer product broadcast.
__global__ void k_xw1(const float* __restrict__ x, const float* __restrict__ W1,
                      float* __restrict__ xw, int N) {
    int t = blockIdx.x * blockDim.x + threadIdx.x;
    if (t >= N * 32) return;
    int i = t >> 5, c = t & 31;
    float4 w = reinterpret_cast<const float4*>(W1)[c];
    float xv = x[i];
    float4 o;
    o.x = xv * w.x; o.y = xv * w.y; o.z = xv * w.z; o.w = xv * w.w;
    reinterpret_cast<float4*>(xw)[t] = o;
}

// Edge-parallel scatter: agg[dst] += xw[src] * norm. F4 = F/4 float4 chunks per row.
template<int F4>
__global__ void k_scatter(const int* __restrict__ src, const int* __restrict__ dst,
                          const float* __restrict__ norm, const float* __restrict__ xw,
                          float* __restrict__ agg, int E) {
    int t = blockIdx.x * blockDim.x + threadIdx.x;
    if (t >= E * F4) return;
    int e = t / F4, c = t % F4;
    int s = src[e], d = dst[e];
    float nrm = norm[e];
    float4 v = reinterpret_cast<const float4*>(xw)[s * F4 + c];
    float* a = agg + (d * F4 + c) * 4;
    atomicAdd(a + 0, v.x * nrm);
    atomicAdd(a + 1, v.y * nrm);
    atomicAdd(a + 2, v.z * nrm);
    atomicAdd(a + 3, v.w * nrm);
}

// h = relu(agg + xw * dinv^2 + b), in place over agg.
template<int F4>
__global__ void k_finalize(const float* __restrict__ xw, const float* __restrict__ dinv,
                           const float* __restrict__ b, float* __restrict__ agg, int N) {
    int t = blockIdx.x * blockDim.x + threadIdx.x;
    if (t >= N * F4) return;
    int i = t / F4, c = t % F4;
    float d2 = dinv[i];
    d2 *= d2;
    float4 xv = reinterpret_cast<const float4*>(xw)[t];
    float4 av = reinterpret_cast<float4*>(agg)[t];
    float4 bv = reinterpret_cast<const float4*>(b)[c];
    float4 r;
    r.x = fmaxf(av.x + xv.x * d2 + bv.x, 0.f);
    r.y = fmaxf(av.y + xv.y * d2 + bv.y, 0.f);
    r.z = fmaxf(av.z + xv.z * d2 + bv.z, 0.f);
    r.w = fmaxf(av.w + xv.w * d2 + bv.w, 0.f);
    reinterpret_cast<float4*>(agg)[t] = r;
}

// Small dense layer: xw[N,FOUT] = h[N,FIN] @ W[FIN,FOUT]; W staged in LDS.
template<int FIN, int FOUT>
__global__ void k_gemm(const float* __restrict__ h, const float* __restrict__ W,
                       float* __restrict__ xw, int N) {
    __shared__ float Ws[FIN * FOUT];
    for (int idx = threadIdx.x; idx < FIN * FOUT; idx += blockDim.x) Ws[idx] = W[idx];
    __syncthreads();
    constexpr int ROWS = THREADS / FOUT;
    int col = threadIdx.x % FOUT;
    int r   = threadIdx.x / FOUT;
    int row = blockIdx.x * ROWS + r;
    if (row >= N) return;
    const float* hp = h + (size_t)row * FIN;
    float acc = 0.f;
#pragma unroll
    for (int k = 0; k < FIN; ++k) acc = fmaf(hp[k], Ws[k * FOUT + col], acc);
    xw[(size_t)row * FOUT + col] = acc;
}

__global__ void k_cnt(const int* __restrict__ batch, float* __restrict__ cnt, int N) {
    int t = blockIdx.x * blockDim.x + threadIdx.x;
    if (t < N) atomicAdd(&cnt[batch[t]], 1.0f);
}

__global__ void k_pool(const float* __restrict__ h3, const int* __restrict__ batch,
                       float* __restrict__ sums, int N) {
    int t = blockIdx.x * blockDim.x + threadIdx.x;
    if (t >= N * 32) return;
    int i = t >> 5, f = t & 31;
    atomicAdd(&sums[batch[i] * 32 + f], h3[t]);
}

__global__ void k_fc(const float* __restrict__ sums, const float* __restrict__ cnt,
                     const float* __restrict__ Wfc, const float* __restrict__ bfc,
                     float* __restrict__ out) {
    int t = blockIdx.x * blockDim.x + threadIdx.x;
    if (t >= 64 * 10) return;
    int g = t / 10, o = t % 10;
    float inv = 1.0f / fmaxf(cnt[g], 1.0f);
    float acc = bfc[o];
#pragma unroll
    for (int f = 0; f < 32; ++f) acc = fmaf(sums[g * 32 + f] * inv, Wfc[f * 10 + o], acc);
    out[t] = acc;
}

extern "C" void kernel_launch(void* const* d_in, const int* in_sizes, int n_in,
                              void* d_out, int out_size, void* d_ws, size_t ws_size,
                              hipStream_t stream) {
    const float* x    = (const float*)d_in[0];
    const int*   ei   = (const int*)d_in[1];
    const int*   batch= (const int*)d_in[2];
    const float* W1   = (const float*)d_in[3];
    const float* b1   = (const float*)d_in[4];
    const float* W2   = (const float*)d_in[5];
    const float* b2   = (const float*)d_in[6];
    const float* W3   = (const float*)d_in[7];
    const float* b3   = (const float*)d_in[8];
    const float* Wfc  = (const float*)d_in[9];
    const float* bfc  = (const float*)d_in[10];
    float* out = (float*)d_out;

    const int N = in_sizes[0];      // F_in == 1, so x has N elements
    const int E = in_sizes[1] / 2;
    const int* src  = ei;
    const int* dstp = ei + E;

    float* ws = (float*)d_ws;
    size_t off = 0;
    float* dinv = ws + off; off += (size_t)N;
    float* norm = ws + off; off += (size_t)E;
    float* sums = ws + off; off += 64 * 32;
    float* cnt  = ws + off; off += 64;
    off = (off + 15) & ~(size_t)15;
    float* A = ws + off; off += (size_t)N * 128;
    float* B = ws + off; off += (size_t)N * 128;

    auto blocks = [](long n) { return (int)((n + THREADS - 1) / THREADS); };

    // Zero the accumulators that need it.
    hipMemsetAsync(dinv, 0, (size_t)N * sizeof(float), stream);
    hipMemsetAsync(sums, 0, (64 * 32 + 64) * sizeof(float), stream);
    hipMemsetAsync(B, 0, (size_t)N * 128 * sizeof(float), stream);

    // Degree / normalization.
    k_deg <<<blocks(E), THREADS, 0, stream>>>(dstp, dinv, E);
    k_dinv<<<blocks(N), THREADS, 0, stream>>>(dinv, N);
    k_norm<<<blocks(E), THREADS, 0, stream>>>(src, dstp, dinv, norm, E);

    // ---- Layer 1 (F=128): xw1 in A, agg1/h1 in B ----
    k_xw1<<<blocks((long)N * 32), THREADS, 0, stream>>>(x, W1, A, N);
    k_scatter<32><<<blocks((long)E * 32), THREADS, 0, stream>>>(src, dstp, norm, A, B, E);
    k_finalize<32><<<blocks((long)N * 32), THREADS, 0, stream>>>(A, dinv, b1, B, N);

    // ---- Layer 2 (F=64): xw2 in A[0:N*64], agg2/h2 in A[N*64:] ----
    k_gemm<128, 64><<<(N + 3) / 4, THREADS, 0, stream>>>(B, W2, A, N);
    hipMemsetAsync(A + (size_t)N * 64, 0, (size_t)N * 64 * sizeof(float), stream);
    k_scatter<16><<<blocks((long)E * 16), THREADS, 0, stream>>>(src, dstp, norm, A, A + (size_t)N * 64, E);
    k_finalize<16><<<blocks((long)N * 16), THREADS, 0, stream>>>(A, dinv, b2, A + (size_t)N * 64, N);

    // ---- Layer 3 (F=32): xw3 in B[0:N*32], agg3/h3 in B[N*32:] ----
    k_gemm<64, 32><<<(N + 7) / 8, THREADS, 0, stream>>>(A + (size_t)N * 64, W3, B, N);
    hipMemsetAsync(B + (size_t)N * 32, 0, (size_t)N * 32 * sizeof(float), stream);
    k_scatter<8><<<blocks((long)E * 8), THREADS, 0, stream>>>(src, dstp, norm, B, B + (size_t)N * 32, E);
    k_finalize<8><<<blocks((long)N * 8), THREADS, 0, stream>>>(B, dinv, b3, B + (size_t)N * 32, N);

    // ---- Pool + FC ----
    k_cnt <<<blocks(N), THREADS, 0, stream>>>(batch, cnt, N);
    k_pool<<<blocks((long)N * 32), THREADS, 0, stream>>>(B + (size_t)N * 32, batch, sums, N);
    k_fc  <<<blocks(640), THREADS, 0, stream>>>(sums, cnt, Wfc, bfc, out);
}

// Round 2
// 421.202 us; speedup vs baseline: 5.6170x; 5.6170x over previous
//
#include <hip/hip_runtime.h>

#define THREADS 256

// ---------------- CSR build ----------------

__global__ void k_count(const int* __restrict__ dst, int* __restrict__ counts, int E) {
    int t = blockIdx.x * blockDim.x + threadIdx.x;
    if (t < E) atomicAdd(&counts[dst[t]], 1);
}

__global__ void k_dinv(const int* __restrict__ counts, float* __restrict__ dinv, int N) {
    int t = blockIdx.x * blockDim.x + threadIdx.x;
    if (t < N) dinv[t] = rsqrtf((float)counts[t] + 1.0f);
}

// Exclusive scan of counts -> rowstart, per 256-block, with block totals.
__global__ void k_scan1(const int* __restrict__ counts, int* __restrict__ rowstart,
                        int* __restrict__ blocksums) {
    __shared__ int s[256];
    int i = blockIdx.x * 256 + threadIdx.x;
    int c = counts[i];
    s[threadIdx.x] = c;
    __syncthreads();
    for (int off = 1; off < 256; off <<= 1) {
        int v = (threadIdx.x >= off) ? s[threadIdx.x - off] : 0;
        __syncthreads();
        s[threadIdx.x] += v;
        __syncthreads();
    }
    rowstart[i] = s[threadIdx.x] - c;
    if (threadIdx.x == 255) blocksums[blockIdx.x] = s[255];
}

__global__ void k_scan2(int* __restrict__ blocksums, int* __restrict__ blockoff) {
    __shared__ int s[256];
    int c = blocksums[threadIdx.x];
    s[threadIdx.x] = c;
    __syncthreads();
    for (int off = 1; off < 256; off <<= 1) {
        int v = (threadIdx.x >= off) ? s[threadIdx.x - off] : 0;
        __syncthreads();
        s[threadIdx.x] += v;
        __syncthreads();
    }
    blockoff[threadIdx.x] = s[threadIdx.x] - c;
}

__global__ void k_scan3(int* __restrict__ rowstart, const int* __restrict__ blockoff) {
    int i = blockIdx.x * 256 + threadIdx.x;
    rowstart[i] += blockoff[blockIdx.x];
}

__global__ void k_fill(const int* __restrict__ src, const int* __restrict__ dst,
                       const int* __restrict__ rowstart, int* __restrict__ cursor,
                       int* __restrict__ esrc, int E) {
    int e = blockIdx.x * blockDim.x + threadIdx.x;
    if (e >= E) return;
    int d = dst[e];
    int p = rowstart[d] + atomicAdd(&cursor[d], 1);
    esrc[p] = src[e];
}

// ---------------- Dense transforms (output pre-scaled by dinv[row]) ----------------

// Layer 1: x[N,1] @ W1[1,128]; xws = x*dinv outer W1.
__global__ void k_xw1(const float* __restrict__ x, const float* __restrict__ W1,
                      const float* __restrict__ dinv, float* __restrict__ xws, int N) {
    int t = blockIdx.x * blockDim.x + threadIdx.x;
    if (t >= N * 32) return;
    int i = t >> 5, c = t & 31;
    float4 w = reinterpret_cast<const float4*>(W1)[c];
    float xv = x[i] * dinv[i];
    float4 o;
    o.x = xv * w.x; o.y = xv * w.y; o.z = xv * w.z; o.w = xv * w.w;
    reinterpret_cast<float4*>(xws)[t] = o;
}

// xws[N,FOUT] = (h[N,FIN] @ W[FIN,FOUT]) * dinv[row]; W staged in LDS.
template<int FIN, int FOUT>
__global__ void k_gemm(const float* __restrict__ h, const float* __restrict__ W,
                       const float* __restrict__ dinv, float* __restrict__ xws, int N) {
    __shared__ float Ws[FIN * FOUT];
    for (int idx = threadIdx.x; idx < FIN * FOUT; idx += blockDim.x) Ws[idx] = W[idx];
    __syncthreads();
    constexpr int ROWS = THREADS / FOUT;
    int col = threadIdx.x % FOUT;
    int r   = threadIdx.x / FOUT;
    int row = blockIdx.x * ROWS + r;
    if (row >= N) return;
    const float* hp = h + (size_t)row * FIN;
    float acc = 0.f;
#pragma unroll
    for (int k = 0; k < FIN; ++k) acc = fmaf(hp[k], Ws[k * FOUT + col], acc);
    xws[(size_t)row * FOUT + col] = acc * dinv[row];
}

// ---------------- Gather-aggregate (fused self-loop + bias + relu) ----------------
// h[i] = relu( dinv[i] * (xws[i] + sum_{s in in(i)} xws[s]) + b )
template<int F4>
__global__ void k_gather(const int* __restrict__ rowstart, const int* __restrict__ counts,
                         const int* __restrict__ esrc, const float* __restrict__ xws,
                         const float* __restrict__ dinv, const float* __restrict__ b,
                         float* __restrict__ h, int N) {
    int t = blockIdx.x * blockDim.x + threadIdx.x;
    if (t >= N * F4) return;
    int i = t / F4, c = t % F4;
    const float4* x4 = reinterpret_cast<const float4*>(xws);
    float4 acc = x4[i * F4 + c];           // self term (already *dinv[i] once)
    int s0 = rowstart[i], cnt = counts[i];
    for (int p = s0; p < s0 + cnt; ++p) {
        int s = esrc[p];
        float4 v = x4[s * F4 + c];
        acc.x += v.x; acc.y += v.y; acc.z += v.z; acc.w += v.w;
    }
    float di = dinv[i];
    float4 bv = reinterpret_cast<const float4*>(b)[c];
    float4 r;
    r.x = fmaxf(acc.x * di + bv.x, 0.f);
    r.y = fmaxf(acc.y * di + bv.y, 0.f);
    r.z = fmaxf(acc.z * di + bv.z, 0.f);
    r.w = fmaxf(acc.w * di + bv.w, 0.f);
    reinterpret_cast<float4*>(h)[t] = r;
}

// ---------------- Pool (sorted-run reduction) + FC ----------------

#define POOL_CHUNK 512
__global__ void k_pool(const float* __restrict__ h3, const int* __restrict__ batch,
                       float* __restrict__ sums, float* __restrict__ cnt, int N) {
    int f = threadIdx.x & 31;        // feature
    int nl = threadIdx.x >> 5;       // node lane 0..7
    int start = blockIdx.x * POOL_CHUNK;
    int end = min(start + POOL_CHUNK, N);
    float acc = 0.f, ncnt = 0.f;
    int g_cur = -1;
    for (int i = start + nl; i < end; i += 8) {
        int g = batch[i];
        if (g != g_cur) {
            if (g_cur >= 0) {
                atomicAdd(&sums[g_cur * 32 + f], acc);
                if (f == 0) atomicAdd(&cnt[g_cur], ncnt);
            }
            g_cur = g; acc = 0.f; ncnt = 0.f;
        }
        acc += h3[(size_t)i * 32 + f];
        ncnt += 1.f;
    }
    if (g_cur >= 0) {
        atomicAdd(&sums[g_cur * 32 + f], acc);
        if (f == 0) atomicAdd(&cnt[g_cur], ncnt);
    }
}

__global__ void k_fc(const float* __restrict__ sums, const float* __restrict__ cnt,
                     const float* __restrict__ Wfc, const float* __restrict__ bfc,
                     float* __restrict__ out) {
    int t = blockIdx.x * blockDim.x + threadIdx.x;
    if (t >= 64 * 10) return;
    int g = t / 10, o = t % 10;
    float inv = 1.0f / fmaxf(cnt[g], 1.0f);
    float acc = bfc[o];
#pragma unroll
    for (int f = 0; f < 32; ++f) acc = fmaf(sums[g * 32 + f] * inv, Wfc[f * 10 + o], acc);
    out[t] = acc;
}

extern "C" void kernel_launch(void* const* d_in, const int* in_sizes, int n_in,
                              void* d_out, int out_size, void* d_ws, size_t ws_size,
                              hipStream_t stream) {
    const float* x    = (const float*)d_in[0];
    const int*   ei   = (const int*)d_in[1];
    const int*   batch= (const int*)d_in[2];
    const float* W1   = (const float*)d_in[3];
    const float* b1   = (const float*)d_in[4];
    const float* W2   = (const float*)d_in[5];
    const float* b2   = (const float*)d_in[6];
    const float* W3   = (const float*)d_in[7];
    const float* b3   = (const float*)d_in[8];
    const float* Wfc  = (const float*)d_in[9];
    const float* bfc  = (const float*)d_in[10];
    float* out = (float*)d_out;

    const int N = in_sizes[0];
    const int E = in_sizes[1] / 2;
    const int* src  = ei;
    const int* dstp = ei + E;

    char* ws = (char*)d_ws;
    size_t off = 0;
    auto alloc = [&](size_t bytes) { void* p = ws + off; off = (off + bytes + 15) & ~(size_t)15; return p; };
    int*   counts   = (int*)  alloc((size_t)N * 4);
    int*   rowstart = (int*)  alloc((size_t)N * 4);
    int*   cursor   = (int*)  alloc((size_t)N * 4);
    int*   blocksums= (int*)  alloc(256 * 4);
    int*   blockoff = (int*)  alloc(256 * 4);
    int*   esrc     = (int*)  alloc((size_t)E * 4);
    float* dinv     = (float*)alloc((size_t)N * 4);
    float* sums     = (float*)alloc(64 * 32 * 4);
    float* cnt      = (float*)alloc(64 * 4);
    float* A        = (float*)alloc((size_t)N * 128 * 4);
    float* B        = (float*)alloc((size_t)N * 128 * 4);

    auto blocks = [](long n) { return (int)((n + THREADS - 1) / THREADS); };

    hipMemsetAsync(counts, 0, (size_t)N * 4, stream);
    hipMemsetAsync(cursor, 0, (size_t)N * 4, stream);
    hipMemsetAsync(sums, 0, (64 * 32 + 64) * 4, stream);

    // CSR build
    k_count<<<blocks(E), THREADS, 0, stream>>>(dstp, counts, E);
    k_dinv <<<blocks(N), THREADS, 0, stream>>>(counts, dinv, N);
    k_scan1<<<N / 256, 256, 0, stream>>>(counts, rowstart, blocksums);
    k_scan2<<<1, 256, 0, stream>>>(blocksums, blockoff);
    k_scan3<<<N / 256, 256, 0, stream>>>(rowstart, blockoff);
    k_fill <<<blocks(E), THREADS, 0, stream>>>(src, dstp, rowstart, cursor, esrc, E);

    // Layer 1 (F=128): xws1 in A, h1 in B
    k_xw1<<<blocks((long)N * 32), THREADS, 0, stream>>>(x, W1, dinv, A, N);
    k_gather<32><<<blocks((long)N * 32), THREADS, 0, stream>>>(rowstart, counts, esrc, A, dinv, b1, B, N);

    // Layer 2 (F=64): xws2 in A, h2 in B
    k_gemm<128, 64><<<(N + 3) / 4, THREADS, 0, stream>>>(B, W2, dinv, A, N);
    k_gather<16><<<blocks((long)N * 16), THREADS, 0, stream>>>(rowstart, counts, esrc, A, dinv, b2, B, N);

    // Layer 3 (F=32): xws3 in A, h3 in B
    k_gemm<64, 32><<<(N + 7) / 8, THREADS, 0, stream>>>(B, W3, dinv, A, N);
    k_gather<8><<<blocks((long)N * 8), THREADS, 0, stream>>>(rowstart, counts, esrc, A, dinv, b3, B, N);

    // Pool + FC
    k_pool<<<(N + POOL_CHUNK - 1) / POOL_CHUNK, THREADS, 0, stream>>>(B, batch, sums, cnt, N);
    k_fc  <<<blocks(640), THREADS, 0, stream>>>(sums, cnt, Wfc, bfc, out);
}

// Round 3
// 234.913 us; speedup vs baseline: 10.0714x; 1.7930x over previous
//
#include <hip/hip_runtime.h>

#define THREADS 256

// ---------------- CSR build ----------------

__global__ void k_count(const int* __restrict__ dst, int* __restrict__ counts, int E) {
    int t = blockIdx.x * blockDim.x + threadIdx.x;
    if (t < E) atomicAdd(&counts[dst[t]], 1);
}

// dinv = rsqrt(deg+1); s1 = x * dinv  (layer-1 pre-scaled scalar feature)
__global__ void k_prep(const int* __restrict__ counts, const float* __restrict__ x,
                       float* __restrict__ dinv, float* __restrict__ s1, int N) {
    int t = blockIdx.x * blockDim.x + threadIdx.x;
    if (t < N) {
        float d = rsqrtf((float)counts[t] + 1.0f);
        dinv[t] = d;
        s1[t] = x[t] * d;
    }
}

__global__ void k_scan1(const int* __restrict__ counts, int* __restrict__ rowstart,
                        int* __restrict__ blocksums) {
    __shared__ int s[256];
    int i = blockIdx.x * 256 + threadIdx.x;
    int c = counts[i];
    s[threadIdx.x] = c;
    __syncthreads();
    for (int off = 1; off < 256; off <<= 1) {
        int v = (threadIdx.x >= off) ? s[threadIdx.x - off] : 0;
        __syncthreads();
        s[threadIdx.x] += v;
        __syncthreads();
    }
    rowstart[i] = s[threadIdx.x] - c;
    if (threadIdx.x == 255) blocksums[blockIdx.x] = s[255];
}

__global__ void k_scan2(int* __restrict__ blocksums, int* __restrict__ blockoff) {
    __shared__ int s[256];
    int c = blocksums[threadIdx.x];
    s[threadIdx.x] = c;
    __syncthreads();
    for (int off = 1; off < 256; off <<= 1) {
        int v = (threadIdx.x >= off) ? s[threadIdx.x - off] : 0;
        __syncthreads();
        s[threadIdx.x] += v;
        __syncthreads();
    }
    blockoff[threadIdx.x] = s[threadIdx.x] - c;
}

__global__ void k_scan3(int* __restrict__ rowstart, const int* __restrict__ blockoff) {
    int i = blockIdx.x * 256 + threadIdx.x;
    rowstart[i] += blockoff[blockIdx.x];
}

__global__ void k_fill(const int* __restrict__ src, const int* __restrict__ dst,
                       const int* __restrict__ rowstart, int* __restrict__ cursor,
                       int* __restrict__ esrc, int E) {
    int e = blockIdx.x * blockDim.x + threadIdx.x;
    if (e >= E) return;
    int d = dst[e];
    int p = rowstart[d] + atomicAdd(&cursor[d], 1);
    esrc[p] = src[e];
}

// ---------------- Layer-1 scalar aggregation: t[i] = s1[i] + sum s1[src] ----------------
__global__ void k_tsum(const int* __restrict__ rowstart, const int* __restrict__ counts,
                       const int* __restrict__ esrc, const float* __restrict__ s1,
                       float* __restrict__ t, int N) {
    int i = blockIdx.x * blockDim.x + threadIdx.x;
    if (i >= N) return;
    float acc = s1[i];
    int s0 = rowstart[i], cnt = counts[i];
    for (int p = s0; p < s0 + cnt; ++p) acc += s1[esrc[p]];
    t[i] = acc;
}

// ---------------- Fused layer1-activation + layer2 GEMM ----------------
// h1[i][k] = relu(dinv[i]*t[i]*W1[k] + b1[k])   (recomputed from scalar a=dinv*t)
// xws2[i][c] = (sum_k h1[i][k]*W2[k][c]) * dinv[i]
// Thread: 8 rows x 4 cols. Block: 128 rows.
#define L12_R 8
__global__ void k_l1l2(const float* __restrict__ t, const float* __restrict__ dinv,
                       const float* __restrict__ W1, const float* __restrict__ b1,
                       const float* __restrict__ W2, float* __restrict__ xws2, int N) {
    __shared__ float wb[128 * 2];      // interleaved {W1[k], b1[k]}
    __shared__ float W2s[128 * 64];    // 32 KB
    for (int idx = threadIdx.x; idx < 128; idx += 256) {
        wb[idx * 2] = W1[idx];
        wb[idx * 2 + 1] = b1[idx];
    }
    for (int idx = threadIdx.x; idx < 128 * 64 / 4; idx += 256)
        reinterpret_cast<float4*>(W2s)[idx] = reinterpret_cast<const float4*>(W2)[idx];
    __syncthreads();

    int c4 = threadIdx.x & 15;           // 4-col group
    int rg = threadIdx.x >> 4;           // 0..15
    int base = blockIdx.x * (16 * L12_R) + rg * L12_R;

    float a[L12_R];
#pragma unroll
    for (int r = 0; r < L12_R; ++r) {
        int i = base + r;
        a[r] = (i < N) ? dinv[i] * t[i] : 0.f;
    }
    float4 acc[L12_R] = {};
    for (int k = 0; k < 128; ++k) {
        float2 w1b1 = *reinterpret_cast<const float2*>(&wb[k * 2]);
        float4 w2 = *reinterpret_cast<const float4*>(&W2s[k * 64 + c4 * 4]);
#pragma unroll
        for (int r = 0; r < L12_R; ++r) {
            float h = fmaxf(fmaf(a[r], w1b1.x, w1b1.y), 0.f);
            acc[r].x = fmaf(h, w2.x, acc[r].x);
            acc[r].y = fmaf(h, w2.y, acc[r].y);
            acc[r].z = fmaf(h, w2.z, acc[r].z);
            acc[r].w = fmaf(h, w2.w, acc[r].w);
        }
    }
#pragma unroll
    for (int r = 0; r < L12_R; ++r) {
        int i = base + r;
        if (i < N) {
            float di = dinv[i];
            float4 o = acc[r];
            o.x *= di; o.y *= di; o.z *= di; o.w *= di;
            reinterpret_cast<float4*>(xws2)[(size_t)i * 16 + c4] = o;
        }
    }
}

// ---------------- Fused gather2 (+relu+bias) + layer3 GEMM ----------------
// Block: 16 rows. Phase A: gather xws2 rows -> h2 tile in LDS.
// Phase B: xws3 = (h2 @ W3) * dinv.
__global__ void k_l2l3(const int* __restrict__ rowstart, const int* __restrict__ counts,
                       const int* __restrict__ esrc, const float* __restrict__ xws2,
                       const float* __restrict__ dinv, const float* __restrict__ b2,
                       const float* __restrict__ W3, float* __restrict__ xws3, int N) {
    __shared__ float W3s[64 * 32];   // 8 KB
    __shared__ float h2s[16][64];    // 4 KB
    __shared__ float b2s[64];
    for (int idx = threadIdx.x; idx < 64 * 32 / 4; idx += 256)
        reinterpret_cast<float4*>(W3s)[idx] = reinterpret_cast<const float4*>(W3)[idx];
    if (threadIdx.x < 64) b2s[threadIdx.x] = b2[threadIdx.x];
    __syncthreads();

    {
        int c4 = threadIdx.x & 15;       // feature group (4 floats)
        int r  = threadIdx.x >> 4;       // 0..15
        int i  = blockIdx.x * 16 + r;
        if (i < N) {
            const float4* x4 = reinterpret_cast<const float4*>(xws2);
            float4 acc = x4[(size_t)i * 16 + c4];
            int s0 = rowstart[i], cnt = counts[i];
            for (int p = s0; p < s0 + cnt; ++p) {
                int s = esrc[p];
                float4 v = x4[(size_t)s * 16 + c4];
                acc.x += v.x; acc.y += v.y; acc.z += v.z; acc.w += v.w;
            }
            float di = dinv[i];
            float4 bv = *reinterpret_cast<const float4*>(&b2s[c4 * 4]);
            float4 h;
            h.x = fmaxf(fmaf(di, acc.x, bv.x), 0.f);
            h.y = fmaxf(fmaf(di, acc.y, bv.y), 0.f);
            h.z = fmaxf(fmaf(di, acc.z, bv.z), 0.f);
            h.w = fmaxf(fmaf(di, acc.w, bv.w), 0.f);
            *reinterpret_cast<float4*>(&h2s[r][c4 * 4]) = h;
        }
    }
    __syncthreads();
    {
        int c  = threadIdx.x & 15;       // cols c and c+16
        int r2 = threadIdx.x >> 4;
        int i2 = blockIdx.x * 16 + r2;
        if (i2 >= N) return;
        float acc0 = 0.f, acc1 = 0.f;
#pragma unroll
        for (int k = 0; k < 64; ++k) {
            float h = h2s[r2][k];
            acc0 = fmaf(h, W3s[k * 32 + c], acc0);
            acc1 = fmaf(h, W3s[k * 32 + c + 16], acc1);
        }
        float di = dinv[i2];
        xws3[(size_t)i2 * 32 + c] = acc0 * di;
        xws3[(size_t)i2 * 32 + c + 16] = acc1 * di;
    }
}

// ---------------- Fused gather3 (+relu+bias) + mean-pool partial reduction ----------------
// Block: 32 rows, 8 threads/row. LDS per-graph accumulation, flush narrow graph range.
__global__ void k_l3pool(const int* __restrict__ rowstart, const int* __restrict__ counts,
                         const int* __restrict__ esrc, const float* __restrict__ xws3,
                         const float* __restrict__ dinv, const float* __restrict__ b3,
                         const int* __restrict__ batch, float* __restrict__ sums,
                         float* __restrict__ cnt, int N) {
    __shared__ float sl[64 * 32];   // 8 KB
    __shared__ float cl[64];
    for (int idx = threadIdx.x; idx < 64 * 32; idx += 256) sl[idx] = 0.f;
    if (threadIdx.x < 64) cl[threadIdx.x] = 0.f;
    __syncthreads();

    int c4 = threadIdx.x & 7;        // feature group
    int r  = threadIdx.x >> 3;       // 0..31
    int i  = blockIdx.x * 32 + r;
    if (i < N) {
        const float4* x4 = reinterpret_cast<const float4*>(xws3);
        float4 acc = x4[(size_t)i * 8 + c4];
        int s0 = rowstart[i], cc = counts[i];
        for (int p = s0; p < s0 + cc; ++p) {
            int s = esrc[p];
            float4 v = x4[(size_t)s * 8 + c4];
            acc.x += v.x; acc.y += v.y; acc.z += v.z; acc.w += v.w;
        }
        float di = dinv[i];
        const float4 bv = reinterpret_cast<const float4*>(b3)[c4];
        float4 h;
        h.x = fmaxf(fmaf(di, acc.x, bv.x), 0.f);
        h.y = fmaxf(fmaf(di, acc.y, bv.y), 0.f);
        h.z = fmaxf(fmaf(di, acc.z, bv.z), 0.f);
        h.w = fmaxf(fmaf(di, acc.w, bv.w), 0.f);
        int g = batch[i];
        atomicAdd(&sl[g * 32 + c4 * 4 + 0], h.x);
        atomicAdd(&sl[g * 32 + c4 * 4 + 1], h.y);
        atomicAdd(&sl[g * 32 + c4 * 4 + 2], h.z);
        atomicAdd(&sl[g * 32 + c4 * 4 + 3], h.w);
        if (c4 == 0) atomicAdd(&cl[g], 1.f);
    }
    __syncthreads();

    int start = blockIdx.x * 32;
    if (start >= N) return;
    int g0 = batch[start];
    int g1 = batch[min(start + 31, N - 1)];
    int ng = g1 - g0 + 1;
    for (int idx = threadIdx.x; idx < ng * 32; idx += 256) {
        float v = sl[(g0 + idx / 32) * 32 + (idx & 31)];
        if (v != 0.f) atomicAdd(&sums[(g0 + idx / 32) * 32 + (idx & 31)], v);
    }
    for (int idx = threadIdx.x; idx < ng; idx += 256) {
        float v = cl[g0 + idx];
        if (v != 0.f) atomicAdd(&cnt[g0 + idx], v);
    }
}

__global__ void k_fc(const float* __restrict__ sums, const float* __restrict__ cnt,
                     const float* __restrict__ Wfc, const float* __restrict__ bfc,
                     float* __restrict__ out) {
    int t = blockIdx.x * blockDim.x + threadIdx.x;
    if (t >= 64 * 10) return;
    int g = t / 10, o = t % 10;
    float inv = 1.0f / fmaxf(cnt[g], 1.0f);
    float acc = bfc[o];
#pragma unroll
    for (int f = 0; f < 32; ++f) acc = fmaf(sums[g * 32 + f] * inv, Wfc[f * 10 + o], acc);
    out[t] = acc;
}

extern "C" void kernel_launch(void* const* d_in, const int* in_sizes, int n_in,
                              void* d_out, int out_size, void* d_ws, size_t ws_size,
                              hipStream_t stream) {
    const float* x    = (const float*)d_in[0];
    const int*   ei   = (const int*)d_in[1];
    const int*   batch= (const int*)d_in[2];
    const float* W1   = (const float*)d_in[3];
    const float* b1   = (const float*)d_in[4];
    const float* W2   = (const float*)d_in[5];
    const float* b2   = (const float*)d_in[6];
    const float* W3   = (const float*)d_in[7];
    const float* b3   = (const float*)d_in[8];
    const float* Wfc  = (const float*)d_in[9];
    const float* bfc  = (const float*)d_in[10];
    float* out = (float*)d_out;

    const int N = in_sizes[0];
    const int E = in_sizes[1] / 2;
    const int* src  = ei;
    const int* dstp = ei + E;

    char* ws = (char*)d_ws;
    size_t off = 0;
    auto alloc = [&](size_t bytes) { void* p = ws + off; off = (off + bytes + 15) & ~(size_t)15; return p; };
    int*   counts   = (int*)  alloc((size_t)N * 4);
    int*   rowstart = (int*)  alloc((size_t)N * 4);
    int*   cursor   = (int*)  alloc((size_t)N * 4);
    int*   blocksums= (int*)  alloc(256 * 4);
    int*   blockoff = (int*)  alloc(256 * 4);
    int*   esrc     = (int*)  alloc((size_t)E * 4);
    float* dinv     = (float*)alloc((size_t)N * 4);
    float* s1       = (float*)alloc((size_t)N * 4);
    float* tsum     = (float*)alloc((size_t)N * 4);
    float* sums     = (float*)alloc(64 * 32 * 4 + 64 * 4);  // sums then cnt, zeroed together
    float* cnt      = sums + 64 * 32;
    float* xws2     = (float*)alloc((size_t)N * 64 * 4);
    float* xws3     = (float*)alloc((size_t)N * 32 * 4);

    auto blocks = [](long n) { return (int)((n + THREADS - 1) / THREADS); };

    hipMemsetAsync(counts, 0, (size_t)N * 4, stream);
    hipMemsetAsync(cursor, 0, (size_t)N * 4, stream);
    hipMemsetAsync(sums, 0, (64 * 32 + 64) * 4, stream);

    // CSR build + normalization
    k_count<<<blocks(E), THREADS, 0, stream>>>(dstp, counts, E);
    k_prep <<<blocks(N), THREADS, 0, stream>>>(counts, x, dinv, s1, N);
    k_scan1<<<N / 256, 256, 0, stream>>>(counts, rowstart, blocksums);
    k_scan2<<<1, 256, 0, stream>>>(blocksums, blockoff);
    k_scan3<<<N / 256, 256, 0, stream>>>(rowstart, blockoff);
    k_fill <<<blocks(E), THREADS, 0, stream>>>(src, dstp, rowstart, cursor, esrc, E);

    // Layer 1 scalar aggregation
    k_tsum<<<blocks(N), THREADS, 0, stream>>>(rowstart, counts, esrc, s1, tsum, N);

    // Fused layer1-act + layer2 GEMM -> xws2
    k_l1l2<<<(N + 16 * L12_R - 1) / (16 * L12_R), THREADS, 0, stream>>>(tsum, dinv, W1, b1, W2, xws2, N);

    // Fused gather2 + layer3 GEMM -> xws3
    k_l2l3<<<(N + 15) / 16, THREADS, 0, stream>>>(rowstart, counts, esrc, xws2, dinv, b2, W3, xws3, N);

    // Fused gather3 + mean-pool partials
    k_l3pool<<<(N + 31) / 32, THREADS, 0, stream>>>(rowstart, counts, esrc, xws3, dinv, b3, batch, sums, cnt, N);

    // FC head
    k_fc<<<blocks(640), THREADS, 0, stream>>>(sums, cnt, Wfc, bfc, out);
}

// Round 4
// 207.667 us; speedup vs baseline: 11.3928x; 1.1312x over previous
//
#include <hip/hip_runtime.h>
#include <hip/hip_fp16.h>

#define THREADS 256

typedef union { uint2 u; __half2 h[2]; } H4;

// ---------------- CSR build ----------------

// counts[d]++ and record per-edge sequence number (order within row is irrelevant: sum).
__global__ void k_count(const int* __restrict__ dst, int* __restrict__ counts,
                        int* __restrict__ seq, int E) {
    int t = blockIdx.x * blockDim.x + threadIdx.x;
    if (t < E) seq[t] = atomicAdd(&counts[dst[t]], 1);
}

// Fused: per-256-block exclusive scan of counts + dinv/s1 computation.
__global__ void k_scan1(const int* __restrict__ counts, const float* __restrict__ x,
                        float* __restrict__ dinv, float* __restrict__ s1,
                        int* __restrict__ rowstart, int* __restrict__ blocksums) {
    __shared__ int s[256];
    int i = blockIdx.x * 256 + threadIdx.x;
    int c = counts[i];
    float d = rsqrtf((float)c + 1.0f);
    dinv[i] = d;
    s1[i] = x[i] * d;
    s[threadIdx.x] = c;
    __syncthreads();
    for (int off = 1; off < 256; off <<= 1) {
        int v = (threadIdx.x >= off) ? s[threadIdx.x - off] : 0;
        __syncthreads();
        s[threadIdx.x] += v;
        __syncthreads();
    }
    rowstart[i] = s[threadIdx.x] - c;
    if (threadIdx.x == 255) blocksums[blockIdx.x] = s[255];
}

// Fused scan2+scan3: every block scans the 256 block sums in LDS, adds its prefix.
__global__ void k_scan3(int* __restrict__ rowstart, const int* __restrict__ blocksums) {
    __shared__ int s[256];
    int c = blocksums[threadIdx.x];
    s[threadIdx.x] = c;
    __syncthreads();
    for (int off = 1; off < 256; off <<= 1) {
        int v = (threadIdx.x >= off) ? s[threadIdx.x - off] : 0;
        __syncthreads();
        s[threadIdx.x] += v;
        __syncthreads();
    }
    int addv = s[blockIdx.x] - blocksums[blockIdx.x];   // exclusive prefix of this block
    int i = blockIdx.x * 256 + threadIdx.x;
    rowstart[i] += addv;
}

// Atomic-free fill using the seq numbers from k_count.
__global__ void k_fill(const int* __restrict__ src, const int* __restrict__ dst,
                       const int* __restrict__ rowstart, const int* __restrict__ seq,
                       int* __restrict__ esrc, int E) {
    int e = blockIdx.x * blockDim.x + threadIdx.x;
    if (e >= E) return;
    esrc[rowstart[dst[e]] + seq[e]] = src[e];
}

// ---------------- Layer-1 scalar aggregation: t[i] = s1[i] + sum s1[src] ----------------
__global__ void k_tsum(const int* __restrict__ rowstart, const int* __restrict__ counts,
                       const int* __restrict__ esrc, const float* __restrict__ s1,
                       float* __restrict__ t, int N) {
    int i = blockIdx.x * blockDim.x + threadIdx.x;
    if (i >= N) return;
    float acc = s1[i];
    int s0 = rowstart[i], cnt = counts[i];
    for (int p = s0; p < s0 + cnt; ++p) acc += s1[esrc[p]];
    t[i] = acc;
}

// ---------------- Fused layer1-activation + layer2 GEMM (fp16 output) ----------------
// h1[i][k] = relu(dinv[i]*t[i]*W1[k] + b1[k]); xws2[i][:] = (h1[i] @ W2) * dinv[i]
#define L12_R 8
__global__ void k_l1l2(const float* __restrict__ t, const float* __restrict__ dinv,
                       const float* __restrict__ W1, const float* __restrict__ b1,
                       const float* __restrict__ W2, __half* __restrict__ xws2, int N) {
    __shared__ float wb[128 * 2];
    __shared__ float W2s[128 * 64];
    for (int idx = threadIdx.x; idx < 128; idx += 256) {
        wb[idx * 2] = W1[idx];
        wb[idx * 2 + 1] = b1[idx];
    }
    for (int idx = threadIdx.x; idx < 128 * 64 / 4; idx += 256)
        reinterpret_cast<float4*>(W2s)[idx] = reinterpret_cast<const float4*>(W2)[idx];
    __syncthreads();

    int c4 = threadIdx.x & 15;
    int rg = threadIdx.x >> 4;
    int base = blockIdx.x * (16 * L12_R) + rg * L12_R;

    float a[L12_R];
#pragma unroll
    for (int r = 0; r < L12_R; ++r) {
        int i = base + r;
        a[r] = (i < N) ? dinv[i] * t[i] : 0.f;
    }
    float4 acc[L12_R] = {};
    for (int k = 0; k < 128; ++k) {
        float2 w1b1 = *reinterpret_cast<const float2*>(&wb[k * 2]);
        float4 w2 = *reinterpret_cast<const float4*>(&W2s[k * 64 + c4 * 4]);
#pragma unroll
        for (int r = 0; r < L12_R; ++r) {
            float h = fmaxf(fmaf(a[r], w1b1.x, w1b1.y), 0.f);
            acc[r].x = fmaf(h, w2.x, acc[r].x);
            acc[r].y = fmaf(h, w2.y, acc[r].y);
            acc[r].z = fmaf(h, w2.z, acc[r].z);
            acc[r].w = fmaf(h, w2.w, acc[r].w);
        }
    }
#pragma unroll
    for (int r = 0; r < L12_R; ++r) {
        int i = base + r;
        if (i < N) {
            float di = dinv[i];
            H4 o;
            o.h[0] = __floats2half2_rn(acc[r].x * di, acc[r].y * di);
            o.h[1] = __floats2half2_rn(acc[r].z * di, acc[r].w * di);
            reinterpret_cast<uint2*>(xws2)[(size_t)i * 16 + c4] = o.u;
        }
    }
}

// ---------------- Fused gather2 (+relu+bias) + layer3 GEMM (fp16 in/out) ----------------
__global__ void k_l2l3(const int* __restrict__ rowstart, const int* __restrict__ counts,
                       const int* __restrict__ esrc, const __half* __restrict__ xws2,
                       const float* __restrict__ dinv, const float* __restrict__ b2,
                       const float* __restrict__ W3, __half* __restrict__ xws3, int N) {
    __shared__ float W3s[64 * 32];   // 8 KB
    __shared__ float h2s[16][64];    // 4 KB
    __shared__ float b2s[64];
    for (int idx = threadIdx.x; idx < 64 * 32 / 4; idx += 256)
        reinterpret_cast<float4*>(W3s)[idx] = reinterpret_cast<const float4*>(W3)[idx];
    if (threadIdx.x < 64) b2s[threadIdx.x] = b2[threadIdx.x];
    __syncthreads();

    {
        int c4 = threadIdx.x & 15;       // 4-feature group
        int r  = threadIdx.x >> 4;       // 0..15
        int i  = blockIdx.x * 16 + r;
        if (i < N) {
            const uint2* x2 = reinterpret_cast<const uint2*>(xws2);
            H4 p; p.u = x2[(size_t)i * 16 + c4];
            float2 f0 = __half22float2(p.h[0]), f1 = __half22float2(p.h[1]);
            float4 acc = {f0.x, f0.y, f1.x, f1.y};
            int s0 = rowstart[i], cnt = counts[i];
            for (int q = s0; q < s0 + cnt; ++q) {
                int s = esrc[q];
                p.u = x2[(size_t)s * 16 + c4];
                f0 = __half22float2(p.h[0]); f1 = __half22float2(p.h[1]);
                acc.x += f0.x; acc.y += f0.y; acc.z += f1.x; acc.w += f1.y;
            }
            float di = dinv[i];
            float4 bv = *reinterpret_cast<const float4*>(&b2s[c4 * 4]);
            float4 h;
            h.x = fmaxf(fmaf(di, acc.x, bv.x), 0.f);
            h.y = fmaxf(fmaf(di, acc.y, bv.y), 0.f);
            h.z = fmaxf(fmaf(di, acc.z, bv.z), 0.f);
            h.w = fmaxf(fmaf(di, acc.w, bv.w), 0.f);
            *reinterpret_cast<float4*>(&h2s[r][c4 * 4]) = h;
        }
    }
    __syncthreads();
    {
        int c  = threadIdx.x & 15;       // cols 2c, 2c+1
        int r2 = threadIdx.x >> 4;
        int i2 = blockIdx.x * 16 + r2;
        if (i2 >= N) return;
        float acc0 = 0.f, acc1 = 0.f;
#pragma unroll
        for (int k = 0; k < 64; ++k) {
            float h = h2s[r2][k];
            float2 w = *reinterpret_cast<const float2*>(&W3s[k * 32 + 2 * c]);
            acc0 = fmaf(h, w.x, acc0);
            acc1 = fmaf(h, w.y, acc1);
        }
        float di = dinv[i2];
        reinterpret_cast<__half2*>(xws3)[(size_t)i2 * 16 + c] =
            __floats2half2_rn(acc0 * di, acc1 * di);
    }
}

// ---------------- Fused gather3 (+relu+bias) + mean-pool partials (fp16 in) ----------------
__global__ void k_l3pool(const int* __restrict__ rowstart, const int* __restrict__ counts,
                         const int* __restrict__ esrc, const __half* __restrict__ xws3,
                         const float* __restrict__ dinv, const float* __restrict__ b3,
                         const int* __restrict__ batch, float* __restrict__ sums,
                         float* __restrict__ cnt, int N) {
    __shared__ float sl[64 * 32];   // 8 KB
    __shared__ float cl[64];
    for (int idx = threadIdx.x; idx < 64 * 32; idx += 256) sl[idx] = 0.f;
    if (threadIdx.x < 64) cl[threadIdx.x] = 0.f;
    __syncthreads();

    int c4 = threadIdx.x & 7;        // 4-feature group
    int r  = threadIdx.x >> 3;       // 0..31
    int i  = blockIdx.x * 32 + r;
    if (i < N) {
        const uint2* x2 = reinterpret_cast<const uint2*>(xws3);
        H4 p; p.u = x2[(size_t)i * 8 + c4];
        float2 f0 = __half22float2(p.h[0]), f1 = __half22float2(p.h[1]);
        float4 acc = {f0.x, f0.y, f1.x, f1.y};
        int s0 = rowstart[i], cc = counts[i];
        for (int q = s0; q < s0 + cc; ++q) {
            int s = esrc[q];
            p.u = x2[(size_t)s * 8 + c4];
            f0 = __half22float2(p.h[0]); f1 = __half22float2(p.h[1]);
            acc.x += f0.x; acc.y += f0.y; acc.z += f1.x; acc.w += f1.y;
        }
        float di = dinv[i];
        const float4 bv = reinterpret_cast<const float4*>(b3)[c4];
        int g = batch[i];
        atomicAdd(&sl[g * 32 + c4 * 4 + 0], fmaxf(fmaf(di, acc.x, bv.x), 0.f));
        atomicAdd(&sl[g * 32 + c4 * 4 + 1], fmaxf(fmaf(di, acc.y, bv.y), 0.f));
        atomicAdd(&sl[g * 32 + c4 * 4 + 2], fmaxf(fmaf(di, acc.z, bv.z), 0.f));
        atomicAdd(&sl[g * 32 + c4 * 4 + 3], fmaxf(fmaf(di, acc.w, bv.w), 0.f));
        if (c4 == 0) atomicAdd(&cl[g], 1.f);
    }
    __syncthreads();

    int start = blockIdx.x * 32;
    if (start >= N) return;
    int g0 = batch[start];
    int g1 = batch[min(start + 31, N - 1)];
    int ng = g1 - g0 + 1;
    for (int idx = threadIdx.x; idx < ng * 32; idx += 256) {
        float v = sl[(g0 + idx / 32) * 32 + (idx & 31)];
        if (v != 0.f) atomicAdd(&sums[(g0 + idx / 32) * 32 + (idx & 31)], v);
    }
    for (int idx = threadIdx.x; idx < ng; idx += 256) {
        float v = cl[g0 + idx];
        if (v != 0.f) atomicAdd(&cnt[g0 + idx], v);
    }
}

__global__ void k_fc(const float* __restrict__ sums, const float* __restrict__ cnt,
                     const float* __restrict__ Wfc, const float* __restrict__ bfc,
                     float* __restrict__ out) {
    int t = blockIdx.x * blockDim.x + threadIdx.x;
    if (t >= 64 * 10) return;
    int g = t / 10, o = t % 10;
    float inv = 1.0f / fmaxf(cnt[g], 1.0f);
    float acc = bfc[o];
#pragma unroll
    for (int f = 0; f < 32; ++f) acc = fmaf(sums[g * 32 + f] * inv, Wfc[f * 10 + o], acc);
    out[t] = acc;
}

extern "C" void kernel_launch(void* const* d_in, const int* in_sizes, int n_in,
                              void* d_out, int out_size, void* d_ws, size_t ws_size,
                              hipStream_t stream) {
    const float* x    = (const float*)d_in[0];
    const int*   ei   = (const int*)d_in[1];
    const int*   batch= (const int*)d_in[2];
    const float* W1   = (const float*)d_in[3];
    const float* b1   = (const float*)d_in[4];
    const float* W2   = (const float*)d_in[5];
    const float* b2   = (const float*)d_in[6];
    const float* W3   = (const float*)d_in[7];
    const float* b3   = (const float*)d_in[8];
    const float* Wfc  = (const float*)d_in[9];
    const float* bfc  = (const float*)d_in[10];
    float* out = (float*)d_out;

    const int N = in_sizes[0];
    const int E = in_sizes[1] / 2;
    const int* src  = ei;
    const int* dstp = ei + E;

    char* ws = (char*)d_ws;
    size_t off = 0;
    auto alloc = [&](size_t bytes) { void* p = ws + off; off = (off + bytes + 15) & ~(size_t)15; return p; };
    int*    counts   = (int*)   alloc((size_t)N * 4);
    int*    rowstart = (int*)   alloc((size_t)N * 4);
    int*    seq      = (int*)   alloc((size_t)E * 4);
    int*    blocksums= (int*)   alloc(256 * 4);
    int*    esrc     = (int*)   alloc((size_t)E * 4);
    float*  dinv     = (float*) alloc((size_t)N * 4);
    float*  s1       = (float*) alloc((size_t)N * 4);
    float*  tsum     = (float*) alloc((size_t)N * 4);
    float*  sums     = (float*) alloc(64 * 32 * 4 + 64 * 4);
    float*  cnt      = sums + 64 * 32;
    __half* xws2     = (__half*)alloc((size_t)N * 64 * 2);
    __half* xws3     = (__half*)alloc((size_t)N * 32 * 2);

    auto blocks = [](long n) { return (int)((n + THREADS - 1) / THREADS); };

    hipMemsetAsync(counts, 0, (size_t)N * 4, stream);
    hipMemsetAsync(sums, 0, (64 * 32 + 64) * 4, stream);

    // CSR build + normalization
    k_count<<<blocks(E), THREADS, 0, stream>>>(dstp, counts, seq, E);
    k_scan1<<<N / 256, 256, 0, stream>>>(counts, x, dinv, s1, rowstart, blocksums);
    k_scan3<<<N / 256, 256, 0, stream>>>(rowstart, blocksums);
    k_fill <<<blocks(E), THREADS, 0, stream>>>(src, dstp, rowstart, seq, esrc, E);

    // Layer 1 scalar aggregation
    k_tsum<<<blocks(N), THREADS, 0, stream>>>(rowstart, counts, esrc, s1, tsum, N);

    // Fused layer1-act + layer2 GEMM -> xws2 (fp16)
    k_l1l2<<<(N + 16 * L12_R - 1) / (16 * L12_R), THREADS, 0, stream>>>(tsum, dinv, W1, b1, W2, xws2, N);

    // Fused gather2 + layer3 GEMM -> xws3 (fp16)
    k_l2l3<<<(N + 15) / 16, THREADS, 0, stream>>>(rowstart, counts, esrc, xws2, dinv, b2, W3, xws3, N);

    // Fused gather3 + mean-pool partials
    k_l3pool<<<(N + 31) / 32, THREADS, 0, stream>>>(rowstart, counts, esrc, xws3, dinv, b3, batch, sums, cnt, N);

    // FC head
    k_fc<<<blocks(640), THREADS, 0, stream>>>(sums, cnt, Wfc, bfc, out);
}